// Round 4
// baseline (71.763 us; speedup 1.0000x reference)
//
#include <hip/hip_runtime.h>

#define HH 64
#define WW 64
#define TT 16
#define NPIX (HH * WW * TT)   // 65536

// lane i <- lane i-1 within 16-lane DPP rows (row_shr:1), 0-fill at row start.
__device__ __forceinline__ float dpp_up1(float x) {
    return __int_as_float(__builtin_amdgcn_update_dpp(
        0, __float_as_int(x), 0x111, 0xF, 0xF, true));
}
// lane i <- lane i+1 within 16-lane DPP rows (row_shl:1), 0-fill at row end.
__device__ __forceinline__ float dpp_dn1(float x) {
    return __int_as_float(__builtin_amdgcn_update_dpp(
        0, __float_as_int(x), 0x101, 0xF, 0xF, true));
}

// Block = 512 threads = 8 waves = 8 column-splits of the 7x7 (dh,dw) grid.
// Wave layout: 4 (h,w) pixels x 16 t (tg = lane & 15 == t). The dt = +-1
// halo is a +-1 lane shift inside a 16-lane DPP row -- garbage at row
// boundaries lands exactly on the t-OOB-masked lanes (tg==0 / tg==15).
// Grid = 1024 blocks -> 8192 waves = 8 waves/SIMD (32/CU).
__global__ __launch_bounds__(512, 8) void statdenoise_kernel(
    const float* __restrict__ img,
    const float* __restrict__ gui,
    const float* __restrict__ est,
    const float* __restrict__ var,
    float* __restrict__ out)
{
    const float SIG[9] = {0.1f, 0.1f, 0.1f, 50.0f, 50.0f, 50.0f, 10.0f, 10.0f, 10.0f};
    const float G2 = 2.907f * 2.907f;   // gamma^2

    const int lane = threadIdx.x & 63;
    const int s    = threadIdx.x >> 6;          // wave id == split 0..7
    const int tg   = lane & 15;                 // t == tg
    const int hwl  = lane >> 4;                 // 0..3
    const int hw   = blockIdx.x * 4 + hwl;      // 4 consecutive (h,w) per block
    const int h    = hw >> 6;                   // block-uniform (4-span never crosses h)
    const int w    = hw & 63;
    const int cpx  = hw * 16 + tg;

    // center values
    float gc[9];
#pragma unroll
    for (int c = 0; c < 9; ++c) gc[c] = gui[c * NPIX + cpx];
    float ec[3], vc[3];
#pragma unroll
    for (int c = 0; c < 3; ++c) {
        ec[c] = est[c * NPIX + cpx];
        vc[c] = var[c * NPIX + cpx];
    }

    const bool vLo = (tg > 0);     // dt=-1 valid  (also masks DPP row-start garbage)
    const bool vHi = (tg < 15);    // dt=+1 valid  (also masks DPP row-end garbage)

    float acc[4] = {0.f, 0.f, 0.f, 0.f};   // r,g,b,wsum

    int dh = s / 7 - 3, dw = s % 7 - 3;    // column r = s, then += 8
    for (int r = s; r < 49; r += 8) {
        const int hh = h + dh;                       // wave-uniform
        if ((unsigned)hh < (unsigned)HH) {
            const int ww   = w + dw;                 // per-lane
            const bool colOK = (unsigned)ww < (unsigned)WW;
            const int wwc  = colOK ? ww : (ww < 0 ? 0 : WW - 1);   // clamp: safe loads
            const int off0 = (((hh << 6) + wwc) << 4) + tg;

            // ---- bilateral over 9 guidance channels, 3 dt-pairs ----
            float sb[3] = {0.f, 0.f, 0.f};
#pragma unroll
            for (int c = 0; c < 9; ++c) {
                float m = gui[c * NPIX + off0];
                float nv[3] = {dpp_up1(m), m, dpp_dn1(m)};   // t-1, t, t+1
#pragma unroll
                for (int k = 0; k < 3; ++k) {
                    float d = gc[c] - nv[k];
                    sb[k] = fmaf(d * d, SIG[c], sb[k]);
                }
            }

            // ---- membership (division-free Welch t-test) ----
            // (OOB h/w neighbors provably get weight 0 in the reference, so
            //  skipping them is exact; center pair passes naturally: d2==0.)
            bool mem[3] = {true, true, true};
#pragma unroll
            for (int c = 0; c < 3; ++c) {
                float em = est[c * NPIX + off0];
                float vm = var[c * NPIX + off0];
                float env[3] = {dpp_up1(em), em, dpp_dn1(em)};
                float vnv[3] = {dpp_up1(vm), vm, dpp_dn1(vm)};
#pragma unroll
                for (int k = 0; k < 3; ++k) {
                    float d  = ec[c] - env[k];
                    float d2 = d * d;
                    float V  = vc[c] + vnv[k];
                    bool pass = (d2 < G2 * V) | ((d2 == 0.f) & (V == 0.f));
                    bool kill = ((vc[c] == 0.f) | (vnv[k] == 0.f)) & (d2 != 0.f);
                    mem[k] = mem[k] & pass & (!kill);
                }
            }

            // ---- weights ----
            float wt[3];
#pragma unroll
            for (int k = 0; k < 3; ++k) {
                bool ok = colOK && mem[k];
                if (k == 0) ok = ok && vLo;
                if (k == 2) ok = ok && vHi;
                wt[k] = ok ? __expf(-0.5f * sb[k]) : 0.f;
            }

            // ---- accumulate image ----
#pragma unroll
            for (int c = 0; c < 3; ++c) {
                float im = img[c * NPIX + off0];
                float iv[3] = {dpp_up1(im), im, dpp_dn1(im)};
                acc[c] = fmaf(wt[0], iv[0], fmaf(wt[1], iv[1], fmaf(wt[2], iv[2], acc[c])));
            }
            acc[3] += wt[0] + wt[1] + wt[2];
        }
        dw += 8;
        while (dw > 3) { dw -= 7; ++dh; }
    }

    // ---- combine the 8 splits through LDS ----
    __shared__ float4 red[8][64];
    red[s][lane] = make_float4(acc[0], acc[1], acc[2], acc[3]);
    __syncthreads();

    if (threadIdx.x < 64) {
        float4 sum = red[0][lane];
#pragma unroll
        for (int q = 1; q < 8; ++q) {
            float4 v = red[q][lane];
            sum.x += v.x; sum.y += v.y; sum.z += v.z; sum.w += v.w;
        }
        const int px = blockIdx.x * 64 + lane;   // == hw*16 + tg
        const float inv = 1.f / sum.w;           // wsum >= 1 (center weight == 1)
        out[0 * NPIX + px] = sum.x * inv;
        out[1 * NPIX + px] = sum.y * inv;
        out[2 * NPIX + px] = sum.z * inv;
    }
}

extern "C" void kernel_launch(void* const* d_in, const int* in_sizes, int n_in,
                              void* d_out, int out_size, void* d_ws, size_t ws_size,
                              hipStream_t stream) {
    const float* img = (const float*)d_in[0];
    const float* gui = (const float*)d_in[1];
    const float* est = (const float*)d_in[2];
    const float* var = (const float*)d_in[3];
    float* out = (float*)d_out;

    dim3 grid(4096 / 4);    // 1024 blocks: 4 (h,w) x 16 t pixels, 8 splits each
    dim3 block(512);
    statdenoise_kernel<<<grid, block, 0, stream>>>(img, gui, est, var, out);
}

// Round 5
// 64.455 us; speedup vs baseline: 1.1134x; 1.1134x over previous
//
#include <hip/hip_runtime.h>

#define HH 64
#define WW 64
#define TT 16
#define NPIX (HH * WW * TT)   // 65536

// lane i <- lane i-1 within 16-lane DPP rows (row_shr:1), 0-fill at row start.
__device__ __forceinline__ float dpp_up1(float x) {
    return __int_as_float(__builtin_amdgcn_update_dpp(
        0, __float_as_int(x), 0x111, 0xF, 0xF, true));
}
// lane i <- lane i+1 within 16-lane DPP rows (row_shl:1), 0-fill at row end.
__device__ __forceinline__ float dpp_dn1(float x) {
    return __int_as_float(__builtin_amdgcn_update_dpp(
        0, __float_as_int(x), 0x101, 0xF, 0xF, true));
}

// Block = 512 threads = 8 waves = 8 column-splits of the 7x7 (dh,dw) grid.
// Wave layout: 4 (h,w) pixels x 16 t (t == lane & 15). dt = +-1 halo via
// +-1-lane DPP shift inside a 16-lane row (boundary garbage == t-OOB lanes).
// XCD swizzle: block b -> (b%8)*128 + b/8, so XCD x owns the contiguous
// h-slab [8x, 8x+8) and its ~1.0 MB working set stays L2-resident across
// the 49x neighbor re-reads (round-4 fetch blowup fix).
__global__ __launch_bounds__(512, 8) void statdenoise_kernel(
    const float* __restrict__ img,
    const float* __restrict__ gui,
    const float* __restrict__ est,
    const float* __restrict__ var,
    float* __restrict__ out)
{
    const float SIG[9] = {0.1f, 0.1f, 0.1f, 50.0f, 50.0f, 50.0f, 10.0f, 10.0f, 10.0f};
    const float G2 = 2.907f * 2.907f;   // gamma^2

    const int bswz = ((blockIdx.x & 7) << 7) + (blockIdx.x >> 3);  // bijective, 1024%8==0
    const int lane = threadIdx.x & 63;
    const int s    = threadIdx.x >> 6;          // wave id == split 0..7
    const int tg   = lane & 15;                 // t == tg
    const int hwl  = lane >> 4;                 // 0..3
    const int hw   = bswz * 4 + hwl;            // 4 consecutive (h,w) per block
    const int h    = hw >> 6;                   // block-uniform (4-span never crosses h)
    const int w    = hw & 63;
    const int cpx  = hw * 16 + tg;

    // center values
    float gc[9];
#pragma unroll
    for (int c = 0; c < 9; ++c) gc[c] = gui[c * NPIX + cpx];
    float ec[3], vc[3];
#pragma unroll
    for (int c = 0; c < 3; ++c) {
        ec[c] = est[c * NPIX + cpx];
        vc[c] = var[c * NPIX + cpx];
    }

    const bool vLo = (tg > 0);     // dt=-1 valid  (also masks DPP row-start garbage)
    const bool vHi = (tg < 15);    // dt=+1 valid  (also masks DPP row-end garbage)

    float acc[4] = {0.f, 0.f, 0.f, 0.f};   // r,g,b,wsum

    int dh = s / 7 - 3, dw = s % 7 - 3;    // column r = s, then += 8
    for (int r = s; r < 49; r += 8) {
        const int hh = h + dh;                       // wave-uniform
        if ((unsigned)hh < (unsigned)HH) {
            const int ww   = w + dw;                 // per-lane
            const bool colOK = (unsigned)ww < (unsigned)WW;
            const int wwc  = colOK ? ww : (ww < 0 ? 0 : WW - 1);   // clamp: safe loads
            const int off0 = (((hh << 6) + wwc) << 4) + tg;

            // ---- bilateral over 9 guidance channels, 3 dt-pairs ----
            float sb[3] = {0.f, 0.f, 0.f};
#pragma unroll
            for (int c = 0; c < 9; ++c) {
                float m = gui[c * NPIX + off0];
                float nv[3] = {dpp_up1(m), m, dpp_dn1(m)};   // t-1, t, t+1
#pragma unroll
                for (int k = 0; k < 3; ++k) {
                    float d = gc[c] - nv[k];
                    sb[k] = fmaf(d * d, SIG[c], sb[k]);
                }
            }

            // ---- membership (division-free Welch t-test) ----
            // (OOB h/w neighbors provably get weight 0 in the reference, so
            //  skipping them is exact; center pair passes naturally: d2==0.)
            bool mem[3] = {true, true, true};
#pragma unroll
            for (int c = 0; c < 3; ++c) {
                float em = est[c * NPIX + off0];
                float vm = var[c * NPIX + off0];
                float env[3] = {dpp_up1(em), em, dpp_dn1(em)};
                float vnv[3] = {dpp_up1(vm), vm, dpp_dn1(vm)};
#pragma unroll
                for (int k = 0; k < 3; ++k) {
                    float d  = ec[c] - env[k];
                    float d2 = d * d;
                    float V  = vc[c] + vnv[k];
                    bool pass = (d2 < G2 * V) | ((d2 == 0.f) & (V == 0.f));
                    bool kill = ((vc[c] == 0.f) | (vnv[k] == 0.f)) & (d2 != 0.f);
                    mem[k] = mem[k] & pass & (!kill);
                }
            }

            // ---- weights ----
            float wt[3];
#pragma unroll
            for (int k = 0; k < 3; ++k) {
                bool ok = colOK && mem[k];
                if (k == 0) ok = ok && vLo;
                if (k == 2) ok = ok && vHi;
                wt[k] = ok ? __expf(-0.5f * sb[k]) : 0.f;
            }

            // ---- accumulate image ----
#pragma unroll
            for (int c = 0; c < 3; ++c) {
                float im = img[c * NPIX + off0];
                float iv[3] = {dpp_up1(im), im, dpp_dn1(im)};
                acc[c] = fmaf(wt[0], iv[0], fmaf(wt[1], iv[1], fmaf(wt[2], iv[2], acc[c])));
            }
            acc[3] += wt[0] + wt[1] + wt[2];
        }
        dw += 8;
        while (dw > 3) { dw -= 7; ++dh; }
    }

    // ---- combine the 8 splits through LDS ----
    __shared__ float4 red[8][64];
    red[s][lane] = make_float4(acc[0], acc[1], acc[2], acc[3]);
    __syncthreads();

    if (threadIdx.x < 64) {
        float4 sum = red[0][lane];
#pragma unroll
        for (int q = 1; q < 8; ++q) {
            float4 v = red[q][lane];
            sum.x += v.x; sum.y += v.y; sum.z += v.z; sum.w += v.w;
        }
        const int px = bswz * 64 + lane;         // == hw*16 + tg
        const float inv = 1.f / sum.w;           // wsum >= 1 (center weight == 1)
        out[0 * NPIX + px] = sum.x * inv;
        out[1 * NPIX + px] = sum.y * inv;
        out[2 * NPIX + px] = sum.z * inv;
    }
}

extern "C" void kernel_launch(void* const* d_in, const int* in_sizes, int n_in,
                              void* d_out, int out_size, void* d_ws, size_t ws_size,
                              hipStream_t stream) {
    const float* img = (const float*)d_in[0];
    const float* gui = (const float*)d_in[1];
    const float* est = (const float*)d_in[2];
    const float* var = (const float*)d_in[3];
    float* out = (float*)d_out;

    dim3 grid(4096 / 4);    // 1024 blocks: 4 (h,w) x 16 t pixels, 8 splits each
    dim3 block(512);
    statdenoise_kernel<<<grid, block, 0, stream>>>(img, gui, est, var, out);
}

// Round 6
// 29.435 us; speedup vs baseline: 2.4380x; 2.1897x over previous
//
#include <hip/hip_runtime.h>

#define HH 64
#define WW 64
#define TT 16
#define NPIX (HH * WW * TT)   // 65536

// lane i <- lane i-1 within 16-lane DPP rows (row_shr:1), 0-fill at row start.
__device__ __forceinline__ float dpp_up1(float x) {
    return __int_as_float(__builtin_amdgcn_update_dpp(
        0, __float_as_int(x), 0x111, 0xF, 0xF, true));
}
// lane i <- lane i+1 within 16-lane DPP rows (row_shl:1), 0-fill at row end.
__device__ __forceinline__ float dpp_dn1(float x) {
    return __int_as_float(__builtin_amdgcn_update_dpp(
        0, __float_as_int(x), 0x101, 0xF, 0xF, true));
}

// Round-3 structure (known-good L2 regime: 512 blocks x 8 waves = 16 waves/CU,
// ~64 resident blocks/XCD -> ~1MB working set fits per-XCD L2 by construction)
// with DPP lane-shifts replacing ds_bpermute shuffles (round-4's one real win).
// Wave = 8 (h,w) x 8 t-groups; each thread owns t = {2tg, 2tg+1}; per column
// each channel is one aligned float2 load; t-halo via +-1-lane DPP. The DPP
// 16-lane row boundary (lanes 7<->8, 0, 15) garbage lands exactly on lanes
// masked by vLo/vHi (t0==0 / t0==14).
__global__ __launch_bounds__(512) void statdenoise_kernel(
    const float* __restrict__ img,
    const float* __restrict__ gui,
    const float* __restrict__ est,
    const float* __restrict__ var,
    float* __restrict__ out)
{
    const float SIG[9] = {0.1f, 0.1f, 0.1f, 50.0f, 50.0f, 50.0f, 10.0f, 10.0f, 10.0f};
    const float G2 = 2.907f * 2.907f;   // gamma^2

    const int lane = threadIdx.x & 63;
    const int s    = threadIdx.x >> 6;          // wave id == split 0..7
    const int tg   = lane & 7;                  // t-group 0..7
    const int hwl  = lane >> 3;                 // 0..7
    const int hw   = blockIdx.x * 8 + hwl;      // 8 consecutive (h,w) per block
    const int h    = hw >> 6;                   // block-uniform
    const int w    = hw & 63;
    const int t0   = tg * 2;                    // owns t0, t0+1
    const int cpx  = hw * 16 + t0;

    // center values (float2 along t)
    float2 gc[9];
#pragma unroll
    for (int c = 0; c < 9; ++c) gc[c] = *(const float2*)&gui[c * NPIX + cpx];
    float2 ec[3], vc[3];
#pragma unroll
    for (int c = 0; c < 3; ++c) {
        ec[c] = *(const float2*)&est[c * NPIX + cpx];
        vc[c] = *(const float2*)&var[c * NPIX + cpx];
    }

    const bool vLo = (t0 != 0);    // dt=-1 for e=0; also masks DPP boundary garbage
    const bool vHi = (t0 != 14);   // dt=+1 for e=1; also masks DPP boundary garbage

    float acc[2][4] = {};   // per owned t: {r,g,b,wsum}

    int dh = s / 7 - 3, dw = s % 7 - 3;   // column r = s, then += 8
    for (int r = s; r < 49; r += 8) {
        const int hh = h + dh;                       // wave-uniform
        if ((unsigned)hh < (unsigned)HH) {
            const int ww   = w + dw;                 // per-lane
            const bool colOK = (unsigned)ww < (unsigned)WW;
            const int wwc  = colOK ? ww : (ww < 0 ? 0 : WW - 1);   // clamp: safe loads
            const int off0 = (((hh << 6) + wwc) << 4) + t0;

            // ---- bilateral over 9 guidance channels, 6 (e,dt) pairs ----
            float sb[2][3] = {};
#pragma unroll
            for (int c = 0; c < 9; ++c) {
                float2 m = *(const float2*)&gui[c * NPIX + off0];
                float nv[4] = {dpp_up1(m.y), m.x, m.y, dpp_dn1(m.x)};  // t0-1..t0+2
#pragma unroll
                for (int e = 0; e < 2; ++e) {
                    float ce = e ? gc[c].y : gc[c].x;
#pragma unroll
                    for (int k = 0; k < 3; ++k) {
                        float d = ce - nv[e + k];
                        sb[e][k] = fmaf(d * d, SIG[c], sb[e][k]);
                    }
                }
            }

            // ---- membership (division-free Welch t-test) ----
            // (OOB h/w neighbors provably get weight 0 in the reference, so
            //  skipping them is exact; center pair passes naturally: d2==0.)
            bool mem[2][3] = {{true, true, true}, {true, true, true}};
#pragma unroll
            for (int c = 0; c < 3; ++c) {
                float2 em = *(const float2*)&est[c * NPIX + off0];
                float2 vm = *(const float2*)&var[c * NPIX + off0];
                float env[4] = {dpp_up1(em.y), em.x, em.y, dpp_dn1(em.x)};
                float vnv[4] = {dpp_up1(vm.y), vm.x, vm.y, dpp_dn1(vm.x)};
#pragma unroll
                for (int e = 0; e < 2; ++e) {
                    float ece = e ? ec[c].y : ec[c].x;
                    float vce = e ? vc[c].y : vc[c].x;
#pragma unroll
                    for (int k = 0; k < 3; ++k) {
                        float d  = ece - env[e + k];
                        float d2 = d * d;
                        float V  = vce + vnv[e + k];
                        bool pass = (d2 < G2 * V) | ((d2 == 0.f) & (V == 0.f));
                        bool kill = ((vce == 0.f) | (vnv[e + k] == 0.f)) & (d2 != 0.f);
                        mem[e][k] = mem[e][k] & pass & (!kill);
                    }
                }
            }

            // ---- weights ----
            float wt[2][3];
#pragma unroll
            for (int e = 0; e < 2; ++e) {
#pragma unroll
                for (int k = 0; k < 3; ++k) {
                    bool ok = colOK && mem[e][k];
                    if (e == 0 && k == 0) ok = ok && vLo;   // tt = t0-1
                    if (e == 1 && k == 2) ok = ok && vHi;   // tt = t0+2
                    wt[e][k] = ok ? __expf(-0.5f * sb[e][k]) : 0.f;
                }
            }

            // ---- accumulate image ----
#pragma unroll
            for (int c = 0; c < 3; ++c) {
                float2 im = *(const float2*)&img[c * NPIX + off0];
                float iv[4] = {dpp_up1(im.y), im.x, im.y, dpp_dn1(im.x)};
#pragma unroll
                for (int e = 0; e < 2; ++e) {
                    acc[e][c] = fmaf(wt[e][0], iv[e],
                                fmaf(wt[e][1], iv[e + 1],
                                fmaf(wt[e][2], iv[e + 2], acc[e][c])));
                }
            }
#pragma unroll
            for (int e = 0; e < 2; ++e)
                acc[e][3] += wt[e][0] + wt[e][1] + wt[e][2];
        }
        dw += 8;
        while (dw > 3) { dw -= 7; ++dh; }
    }

    // ---- combine the 8 splits through LDS ----
    __shared__ float4 red[2][8][64];
    red[0][s][lane] = make_float4(acc[0][0], acc[0][1], acc[0][2], acc[0][3]);
    red[1][s][lane] = make_float4(acc[1][0], acc[1][1], acc[1][2], acc[1][3]);
    __syncthreads();

    if (threadIdx.x < 128) {
        const int j = threadIdx.x;
        const int l = j >> 1, e = j & 1;
        float4 sum = red[e][0][l];
#pragma unroll
        for (int q = 1; q < 8; ++q) {
            float4 v = red[e][q][l];
            sum.x += v.x; sum.y += v.y; sum.z += v.z; sum.w += v.w;
        }
        const int px = blockIdx.x * 128 + j;   // px_local == j by construction
        const float inv = 1.f / sum.w;         // wsum >= 1 (center weight == 1)
        out[0 * NPIX + px] = sum.x * inv;
        out[1 * NPIX + px] = sum.y * inv;
        out[2 * NPIX + px] = sum.z * inv;
    }
}

extern "C" void kernel_launch(void* const* d_in, const int* in_sizes, int n_in,
                              void* d_out, int out_size, void* d_ws, size_t ws_size,
                              hipStream_t stream) {
    const float* img = (const float*)d_in[0];
    const float* gui = (const float*)d_in[1];
    const float* est = (const float*)d_in[2];
    const float* var = (const float*)d_in[3];
    float* out = (float*)d_out;

    dim3 grid(4096 / 8);    // 512 blocks: 8 (h,w) x 16 t pixels, 8 splits each
    dim3 block(512);
    statdenoise_kernel<<<grid, block, 0, stream>>>(img, gui, est, var, out);
}